// Round 13
// baseline (353.400 us; speedup 1.0000x reference)
//
#include <hip/hip_runtime.h>
#include <hip/hip_bf16.h>
#include <stdint.h>

// ---------------------------------------------------------------------------
// RG-LRU block: T=8192, D_MODEL=768, D_RNN=1024, KW=4.
// Round 19: conv -> 512 threads, same 128x128 tile / LDS / swizzle / bytes.
//  - r12 mechanism applied to conv: same tile at 2x threads halves per-wave
//    work and doubles waves/SIMD (2->4): 8 waves x 2 blocks/CU = 16 waves/CU.
//    More independent wave streams cover each other's vmcnt(0) barrier
//    drains (m114) — the exact change that won on the dense GEMMs in r12.
//  - 8 waves as 2m x 4n, each wave 64x32 out, acc[4][2]=32 VGPR,
//    32 MFMA/wave per barrier-pair.
// Everything else byte-identical to r16/r18 (338.7 us measured best):
// classic 512-thr BN=256 gemms, vectorized prep, scalar scans NC=128/CL=64.
// ---------------------------------------------------------------------------

#define T_LEN 8192
#define DM 768
#define DR 1024
#define NC 128   // scan chunks
#define CL 64    // chunk length

typedef __bf16 bf16x8 __attribute__((ext_vector_type(8)));
typedef float  f32x4  __attribute__((ext_vector_type(4)));

#define AS1 __attribute__((address_space(1)))
#define AS3 __attribute__((address_space(3)))

__device__ __forceinline__ void cp16_g2l(const void* g, void* l) {
    __builtin_amdgcn_global_load_lds((const AS1 void*)g, (AS3 void*)l, 16, 0, 0);
}

__device__ __forceinline__ float gelu_tanh(float x) {
    const float inner = 0.7978845608028654f * (x + 0.044715f * x * x * x);
    return 0.5f * x * (1.f + tanhf(inner));
}

// ---------------------------------------------------------------------------
// Dense GEMM: C[m,n] = sum_k A[m,k]*B[n,k] (+bias[n]).  BM=128, BK=64.
// Grid: (M/128, N/BN) — m fastest (id%8 = m%8: all n-blocks of an m-tile
// share one XCD -> A-slice L2-resident).
// LDS rows are 64 elements = 8 16B chunks; chunk slot s at row r holds global
// chunk s ^ (r & 7)  -> every wave64 ds_read_b128 is perfectly bank-balanced.
// BN=256: 512 thr, 8 waves (2m x 4n), 64x64 per wave, NI=4, acc 64 VGPR ->
//         16 waves/CU (4/SIMD) — doubled TLP covers vmcnt(0) drains.
// BN=64:  256 thr, 4 waves (2m x 2n), 64x32 per wave, NI=2.
// EPI: 0 = fp32 +bias; 1 = bf16 +bias; 2 = split (gelu->Cv / shift->D2).
// ---------------------------------------------------------------------------
template<int BN, int EPI>
__global__ __launch_bounds__((BN == 256) ? 512 : 256, (BN == 256) ? 4 : 2)
void gemm_mfma(const __hip_bfloat16* __restrict__ A,
               const __hip_bfloat16* __restrict__ B,
               const float* __restrict__ bias,
               void* __restrict__ Cv,
               int K, int lda, int N,
               __hip_bfloat16* __restrict__ D2)
{
    constexpr int TH  = (BN == 256) ? 512 : 256;   // threads
    constexpr int NWN = (BN == 256) ? 4 : 2;       // n-waves
    constexpr int NI  = BN / (16 * NWN);           // n-frags per wave (4 or 2)
    __shared__ __bf16 As[128 * 64];
    __shared__ __bf16 Bs[BN * 64];

    const int tid  = threadIdx.x;
    const int lane = tid & 63;
    const int wave = tid >> 6;
    const size_t m0 = (size_t)blockIdx.x * 128;   // XCD = blockIdx.x % 8
    const int    n0 = blockIdx.y * BN;
    const int wm = (wave / NWN) * 64;
    const int wn = (wave % NWN) * (NI * 16);

    f32x4 acc[4][NI];
#pragma unroll
    for (int i = 0; i < 4; ++i)
#pragma unroll
        for (int j = 0; j < NI; ++j)
            acc[i][j] = f32x4{0.f, 0.f, 0.f, 0.f};

    const int frow = lane & 15;
    const int fq   = lane >> 4;

    for (int k0 = 0; k0 < K; k0 += 64) {
        __syncthreads();   // previous iteration's LDS reads complete
        // A tile: 128 rows x 8 chunks = 1024 chunks
#pragma unroll
        for (int q = 0; q < 1024 / TH; ++q) {
            const int lin = q * TH + tid;
            const int rr  = lin >> 3;
            const int gc  = (lin & 7) ^ (rr & 7);
            cp16_g2l(A + (m0 + rr) * (size_t)lda + k0 + gc * 8, &As[lin * 8]);
        }
        // B tile: BN rows x 8 chunks
#pragma unroll
        for (int q = 0; q < BN * 8 / TH; ++q) {
            const int lin = q * TH + tid;
            const int rr  = lin >> 3;
            const int gc  = (lin & 7) ^ (rr & 7);
            cp16_g2l(B + (size_t)(n0 + rr) * K + k0 + gc * 8, &Bs[lin * 8]);
        }
        __syncthreads();   // includes vmcnt(0) drain

#pragma unroll
        for (int ks = 0; ks < 2; ++ks) {
            bf16x8 af[4], bfr[NI];
#pragma unroll
            for (int mi = 0; mi < 4; ++mi) {
                const int R = wm + mi * 16 + frow;
                af[mi] = *(const bf16x8*)&As[R * 64 + (((ks * 4 + fq) ^ (R & 7)) * 8)];
            }
#pragma unroll
            for (int ni = 0; ni < NI; ++ni) {
                const int R = wn + ni * 16 + frow;
                bfr[ni] = *(const bf16x8*)&Bs[R * 64 + (((ks * 4 + fq) ^ (R & 7)) * 8)];
            }
#pragma unroll
            for (int mi = 0; mi < 4; ++mi)
#pragma unroll
                for (int ni = 0; ni < NI; ++ni)
                    acc[mi][ni] = __builtin_amdgcn_mfma_f32_16x16x32_bf16(
                        af[mi], bfr[ni], acc[mi][ni], 0, 0, 0);
        }
    }

    // C/D layout: col = lane&15, row = (lane>>4)*4 + reg
    const int er = fq * 4;
    const int ec = frow;
#pragma unroll
    for (int ni = 0; ni < NI; ++ni) {
        const int n = n0 + wn + ni * 16 + ec;
        const float bv = bias ? bias[n] : 0.f;
#pragma unroll
        for (int mi = 0; mi < 4; ++mi) {
#pragma unroll
            for (int r2 = 0; r2 < 4; ++r2) {
                const size_t m = m0 + wm + mi * 16 + er + r2;
                const float v = acc[mi][ni][r2] + bv;
                if (EPI == 0) {
                    ((float*)Cv)[m * (size_t)N + n] = v;
                } else if (EPI == 1) {
                    ((__hip_bfloat16*)Cv)[m * (size_t)N + n] = __float2bfloat16(v);
                } else {
                    if (n < 1024)
                        ((__hip_bfloat16*)Cv)[m * 1024 + n] = __float2bfloat16(gelu_tanh(v));
                    else
                        D2[(m + 3) * 1024 + (n - 1024)] = __float2bfloat16(v);
                }
            }
        }
    }
}

// ---------------------------------------------------------------------------
// Conv GEMM with shift reuse: bc[t,o] = sum_s sum_i W[o][s*1024+i]*bbp[t+s][i].
// 512 threads, 8 waves (2m x 4n), each wave 64x32 output, acc[4][2].
// Per 32-col k-tile: stage A halo (132 rows x 32) ONCE + 4 B shift tiles
// (128 x 32 each) — same LDS layout/swizzle/bytes as the 256-thr r6 body —
// then 4 shifts x 8 MFMA per wave per barrier.  32 k-iters.
// 32-wide rows = 4 chunks; slot s at row r holds chunk s ^ ((r>>1)&3).
// 2 blocks/CU x 8 waves = 16 waves/CU (4/SIMD) — r12 mechanism: wave TLP
// covers the per-iter vmcnt(0) barrier drains.
// ---------------------------------------------------------------------------
__global__ __launch_bounds__(512, 4)
void conv_mfma(const __hip_bfloat16* __restrict__ bbp,
               const __hip_bfloat16* __restrict__ W,
               __hip_bfloat16* __restrict__ C)
{
    __shared__ __bf16 As[132 * 32];        // 8.25 KB halo tile
    __shared__ __bf16 Bs[4 * 128 * 32];    // 32 KB, 4 shift tiles

    const int tid  = threadIdx.x;
    const int lane = tid & 63;
    const int wave = tid >> 6;
    const size_t m0 = (size_t)blockIdx.x * 128;   // XCD = blockIdx.x % 8
    const int    n0 = blockIdx.y * 128;
    const int wm = (wave >> 2) * 64;   // 2 m-halves
    const int wn = (wave & 3) * 32;    // 4 n-quarters

    f32x4 acc[4][2];
#pragma unroll
    for (int i = 0; i < 4; ++i)
#pragma unroll
        for (int j = 0; j < 2; ++j)
            acc[i][j] = f32x4{0.f, 0.f, 0.f, 0.f};

    const int frow = lane & 15;
    const int fq   = lane >> 4;

    for (int kc = 0; kc < 1024; kc += 32) {
        __syncthreads();
        // A halo: 132 rows x 4 chunks = 528 chunks (512 + 16 tail)
        {
            const int lin = tid;
            const int rr  = lin >> 2;
            const int gc  = (lin & 3) ^ ((rr >> 1) & 3);
            cp16_g2l(bbp + (m0 + rr) * 1024 + kc + gc * 8, &As[lin * 8]);
        }
        if (tid < 16) {
            const int lin = 512 + tid;
            const int rr  = lin >> 2;
            const int gc  = (lin & 3) ^ ((rr >> 1) & 3);
            cp16_g2l(bbp + (m0 + rr) * 1024 + kc + gc * 8, &As[lin * 8]);
        }
        // B: 4 shift tiles, each 128 rows x 4 chunks = 512 chunks (1 round)
#pragma unroll
        for (int s = 0; s < 4; ++s) {
            const int lin = tid;
            const int rr  = lin >> 2;
            const int gc  = (lin & 3) ^ ((rr >> 1) & 3);
            cp16_g2l(W + (size_t)(n0 + rr) * 4096 + s * 1024 + kc + gc * 8,
                     &Bs[s * 4096 + lin * 8]);
        }
        __syncthreads();

#pragma unroll
        for (int s = 0; s < 4; ++s) {
            bf16x8 af[4], bfr[2];
#pragma unroll
            for (int mi = 0; mi < 4; ++mi) {
                const int R = wm + mi * 16 + frow + s;       // shifted row
                af[mi] = *(const bf16x8*)&As[R * 32 + ((fq ^ ((R >> 1) & 3)) * 8)];
            }
#pragma unroll
            for (int ni = 0; ni < 2; ++ni) {
                const int R = wn + ni * 16 + frow;
                bfr[ni] = *(const bf16x8*)&Bs[s * 4096 + R * 32 + ((fq ^ ((R >> 1) & 3)) * 8)];
            }
#pragma unroll
            for (int mi = 0; mi < 4; ++mi)
#pragma unroll
                for (int ni = 0; ni < 2; ++ni)
                    acc[mi][ni] = __builtin_amdgcn_mfma_f32_16x16x32_bf16(
                        af[mi], bfr[ni], acc[mi][ni], 0, 0, 0);
        }
    }

    const int er = fq * 4;
    const int ec = frow;
#pragma unroll
    for (int ni = 0; ni < 2; ++ni) {
        const int n = n0 + wn + ni * 16 + ec;
#pragma unroll
        for (int mi = 0; mi < 4; ++mi)
#pragma unroll
            for (int r2 = 0; r2 < 4; ++r2) {
                const size_t m = m0 + wm + mi * 16 + er + r2;
                C[m * 1024 + n] = __float2bfloat16(acc[mi][ni][r2]);
            }
    }
}

// ---------------------------------------------------------------------------
// Vectorized prep: 4 elems/thread for f32->bf16 conversions (float4 load,
// ushort4 store); conv repack 1 thread per (o,i): float4 read of 4 taps,
// 4 coalesced k-plane stores; bbp pad rows zeroed.
// ---------------------------------------------------------------------------
#define G_X   1572864                 // 8192*768/4
#define G_W1  (G_X + 393216)          // + 2048*768/4
#define G_WRG (G_W1 + 524288)         // + 2048*1024/4
#define G_WO  (G_WRG + 196608)        // + 768*1024/4
#define G_CW  (G_WO + 1048576)        // + 1024*1024 (o,i) pairs
#define G_PAD (G_CW + 768)            // + 3072/4 pad groups
#define PREP_BLOCKS (G_PAD / 256)     // 14595

__device__ __forceinline__ unsigned short bfu(float f) {
    __hip_bfloat16 h = __float2bfloat16(f);
    union { __hip_bfloat16 h; unsigned short u; } cv; cv.h = h; return cv.u;
}
__device__ __forceinline__ void cvt4(const float* __restrict__ s,
                                     __hip_bfloat16* __restrict__ d) {
    const float4 v = *(const float4*)s;
    ushort4 o; o.x = bfu(v.x); o.y = bfu(v.y); o.z = bfu(v.z); o.w = bfu(v.w);
    *(ushort4*)d = o;
}

__global__ void prep_kernel(const float* __restrict__ x, const float* __restrict__ w1,
                            const float* __restrict__ w_rg, const float* __restrict__ w_out,
                            const float* __restrict__ conv_w,
                            __hip_bfloat16* __restrict__ xb, __hip_bfloat16* __restrict__ w1b,
                            __hip_bfloat16* __restrict__ w_rgb, __hip_bfloat16* __restrict__ w_outb,
                            __hip_bfloat16* __restrict__ wbigb, __hip_bfloat16* __restrict__ bbp)
{
    const int g = blockIdx.x * 256 + threadIdx.x;
    if (g < G_X) {
        const size_t i = 4 * (size_t)g;            cvt4(x + i, xb + i);
    } else if (g < G_W1) {
        const size_t i = 4 * (size_t)(g - G_X);    cvt4(w1 + i, w1b + i);
    } else if (g < G_WRG) {
        const size_t i = 4 * (size_t)(g - G_W1);   cvt4(w_rg + i, w_rgb + i);
    } else if (g < G_WO) {
        const size_t i = 4 * (size_t)(g - G_WRG);  cvt4(w_out + i, w_outb + i);
    } else if (g < G_CW) {
        const int n = g - G_WO;                    // n = o*1024 + i
        const int o = n >> 10, i = n & 1023;
        const float4 v = *(const float4*)(conv_w + (size_t)n * 4); // 4 taps, contiguous
        __hip_bfloat16* base = wbigb + (size_t)o * 4096 + i;
        base[0]    = __float2bfloat16(v.x);        // k=0 plane (coalesced per k)
        base[1024] = __float2bfloat16(v.y);
        base[2048] = __float2bfloat16(v.z);
        base[3072] = __float2bfloat16(v.w);
    } else if (g < G_PAD) {
        const int i = (g - G_CW) * 4;
        ushort4 z; z.x = 0; z.y = 0; z.z = 0; z.w = 0;
        *(ushort4*)(bbp + i) = z;                  // rows 0..2 zero
    }
}

// Gates recomputed inline from g_pre (T x 2048 bf16) + bc (bf16):
__global__ void scan_pass1(const __hip_bfloat16* __restrict__ gp,
                           const __hip_bfloat16* __restrict__ bc,
                           const float* __restrict__ Lambda,
                           float* __restrict__ ch, float* __restrict__ ca)
{
    const int c = blockIdx.y * 256 + threadIdx.x;
    const int j = blockIdx.x;
    const float cl = -8.f * log1pf(expf(Lambda[c]));
    float h = 0.f, ap = 1.f;
    const int t0 = j * CL;
    for (int tt = 0; tt < CL; ++tt) {
        const int t = t0 + tt;
        const long gi = (long)t * 2048 + c;
        const float ig = 1.f / (1.f + expf(-__bfloat162float(gp[gi])));
        const float rg = 1.f / (1.f + expf(-__bfloat162float(gp[gi + 1024])));
        const float a  = expf(cl * rg);
        const float gx = sqrtf(fmaxf(0.f, 1.f - a * a)) * ig *
                         __bfloat162float(bc[(long)t * 1024 + c]);
        h  = fmaf(a, h, gx);
        ap *= a;
    }
    ch[j * 1024 + c] = h;
    ca[j * 1024 + c] = ap;
}

__global__ void scan_combine(float* __restrict__ ch, const float* __restrict__ ca)
{
    const int c = blockIdx.x * 256 + threadIdx.x;
    float carry = 0.f;
    for (int j = 0; j < NC; ++j) {
        const float hj = ch[j * 1024 + c];
        const float aj = ca[j * 1024 + c];
        ch[j * 1024 + c] = carry;
        carry = fmaf(aj, carry, hj);
    }
}

// Rescan with carry; z = ab * y -> bf16 (zb aliases bc: same-element RMW per thread).
__global__ void scan_pass2(const __hip_bfloat16* __restrict__ gp, const __hip_bfloat16* bc,
                           const float* __restrict__ Lambda,
                           const float* __restrict__ carry_in,
                           const __hip_bfloat16* __restrict__ ab,
                           __hip_bfloat16* zb)
{
    const int c = blockIdx.y * 256 + threadIdx.x;
    const int j = blockIdx.x;
    const float cl = -8.f * log1pf(expf(Lambda[c]));
    float h = carry_in[j * 1024 + c];
    const int t0 = j * CL;
    for (int tt = 0; tt < CL; ++tt) {
        const int t = t0 + tt;
        const long gi = (long)t * 2048 + c;
        const long bi = (long)t * 1024 + c;
        const float ig = 1.f / (1.f + expf(-__bfloat162float(gp[gi])));
        const float rg = 1.f / (1.f + expf(-__bfloat162float(gp[gi + 1024])));
        const float a  = expf(cl * rg);
        const float gx = sqrtf(fmaxf(0.f, 1.f - a * a)) * ig * __bfloat162float(bc[bi]);
        h = fmaf(a, h, gx);
        zb[bi] = __float2bfloat16(__bfloat162float(ab[bi]) * h);
    }
}

extern "C" void kernel_launch(void* const* d_in, const int* in_sizes, int n_in,
                              void* d_out, int out_size, void* d_ws, size_t ws_size,
                              hipStream_t stream)
{
    const float* x      = (const float*)d_in[0];
    const float* w1     = (const float*)d_in[1];
    const float* b1     = (const float*)d_in[2];
    const float* conv_w = (const float*)d_in[3];
    const float* w_rg   = (const float*)d_in[4];
    const float* b_rg   = (const float*)d_in[5];
    const float* w_out  = (const float*)d_in[6];
    const float* b_out  = (const float*)d_in[7];
    const float* Lambda = (const float*)d_in[8];
    float* out = (float*)d_out;
    (void)in_sizes; (void)n_in; (void)out_size; (void)ws_size;

    // ---- workspace layout (~113 MB) ----
    char* p = (char*)d_ws;
    auto alloc = [&](size_t bytes) { char* r = p; p += (bytes + 255) & ~255ULL; return r; };
    __hip_bfloat16* gpre  = (__hip_bfloat16*)alloc(8192ULL * 2048 * 2); // 32 MB
    __hip_bfloat16* ab    = (__hip_bfloat16*)alloc(8192ULL * 1024 * 2); // 16 MB
    __hip_bfloat16* bbp   = (__hip_bfloat16*)alloc(8224ULL * 1024 * 2); // 16.8 MB
    __hip_bfloat16* bcb   = (__hip_bfloat16*)alloc(8192ULL * 1024 * 2); // 16 MB (later zb)
    __hip_bfloat16* wbigb = (__hip_bfloat16*)alloc(1024ULL * 4096 * 2); // 8 MB
    __hip_bfloat16* xb    = (__hip_bfloat16*)alloc(8192ULL * 768 * 2);  // 12 MB
    __hip_bfloat16* w1b   = (__hip_bfloat16*)alloc(2048ULL * 768 * 2);  // 3 MB
    __hip_bfloat16* w_rgb = (__hip_bfloat16*)alloc(2048ULL * 1024 * 2); // 4 MB
    __hip_bfloat16* w_outb= (__hip_bfloat16*)alloc(768ULL * 1024 * 2);  // 1.5 MB
    float*          chv   = (float*)alloc(NC * 1024ULL * 4);
    float*          cav   = (float*)alloc(NC * 1024ULL * 4);
    __hip_bfloat16* zb    = bcb;   // overlay

    prep_kernel<<<PREP_BLOCKS, 256, 0, stream>>>(x, w1, w_rg, w_out, conv_w,
                                                 xb, w1b, w_rgb, w_outb, wbigb, bbp);

    // h = x @ w1.T + b1, fused split: ab = bf16(gelu), bbp = bf16 (rows +3)
    {
        dim3 grid(T_LEN / 128, 2048 / 256);
        gemm_mfma<256, 2><<<grid, 512, 0, stream>>>(xb, w1b, b1, ab, DM, DM, 2048, bbp);
    }

    // bc = causal conv (shift-reuse kernel, 512 thr / 16 waves/CU) -> bf16
    {
        dim3 grid(T_LEN / 128, 1024 / 128);
        conv_mfma<<<grid, 512, 0, stream>>>(bbp, wbigb, bcb);
    }

    // g_pre = bc @ w_rg.T + b_rg -> bf16
    {
        dim3 grid(T_LEN / 128, 2048 / 256);
        gemm_mfma<256, 1><<<grid, 512, 0, stream>>>(bcb, w_rgb, b_rg, gpre, DR, DR, 2048, nullptr);
    }

    // chunked scan with fused gates; z = ab*y -> bf16 (overlays bcb)
    {
        dim3 gs(NC, DR / 256);
        scan_pass1<<<gs, 256, 0, stream>>>(gpre, bcb, Lambda, chv, cav);
        scan_combine<<<DR / 256, 256, 0, stream>>>(chv, cav);
        scan_pass2<<<gs, 256, 0, stream>>>(gpre, bcb, Lambda, chv, ab, zb);
    }

    // out = z @ w_out.T + b_out -> fp32
    {
        dim3 grid(T_LEN / 128, DM / 64);
        gemm_mfma<64, 0><<<grid, 256, 0, stream>>>(zb, w_outb, b_out, out, DR, DR, DM, nullptr);
    }
}

// Round 14
// 352.314 us; speedup vs baseline: 1.0031x; 1.0031x over previous
//
#include <hip/hip_runtime.h>
#include <hip/hip_bf16.h>
#include <stdint.h>

// ---------------------------------------------------------------------------
// RG-LRU block: T=8192, D_MODEL=768, D_RNN=1024, KW=4.
// Round 20 (FINAL): bank the measured-best r16 configuration (338.7 us).
// r19's conv occupancy doubling (512 thr, 16 waves/CU) was a clean
// falsification: Occupancy 19->37 with dur/MfmaUtil unchanged — conv's idle
// is the synchronized per-iter vmcnt(0)+barrier drain, which TLP cannot
// hide (all resident waves drain together) and which intra-block pipelining
// (r7/r11/r15) loses more than it gains at this size.
// Explored-and-rejected vs this config (all measured worse):
//   conv counted-vmcnt/dbuf x3, gemm counted-vmcnt x1, scan vectorization x2,
//   XCD grid transpose x1, conv 2x occupancy x1.
// Config: classic 512-thr BN=256 gemms (16 waves/CU), conv r6 body 256-thr
// (~68 us, MfmaUtil 43%), vectorized prep, scalar scans NC=128/CL=64.
// ---------------------------------------------------------------------------

#define T_LEN 8192
#define DM 768
#define DR 1024
#define NC 128   // scan chunks
#define CL 64    // chunk length

typedef __bf16 bf16x8 __attribute__((ext_vector_type(8)));
typedef float  f32x4  __attribute__((ext_vector_type(4)));

#define AS1 __attribute__((address_space(1)))
#define AS3 __attribute__((address_space(3)))

__device__ __forceinline__ void cp16_g2l(const void* g, void* l) {
    __builtin_amdgcn_global_load_lds((const AS1 void*)g, (AS3 void*)l, 16, 0, 0);
}

__device__ __forceinline__ float gelu_tanh(float x) {
    const float inner = 0.7978845608028654f * (x + 0.044715f * x * x * x);
    return 0.5f * x * (1.f + tanhf(inner));
}

// ---------------------------------------------------------------------------
// Dense GEMM: C[m,n] = sum_k A[m,k]*B[n,k] (+bias[n]).  BM=128, BK=64.
// Grid: (M/128, N/BN) — m fastest (id%8 = m%8: all n-blocks of an m-tile
// share one XCD -> A-slice L2-resident).
// LDS rows are 64 elements = 8 16B chunks; chunk slot s at row r holds global
// chunk s ^ (r & 7)  -> every wave64 ds_read_b128 is perfectly bank-balanced.
// BN=256: 512 thr, 8 waves (2m x 4n), 64x64 per wave, NI=4, acc 64 VGPR ->
//         16 waves/CU (4/SIMD) — doubled TLP covers vmcnt(0) drains.
// BN=64:  256 thr, 4 waves (2m x 2n), 64x32 per wave, NI=2.
// EPI: 0 = fp32 +bias; 1 = bf16 +bias; 2 = split (gelu->Cv / shift->D2).
// ---------------------------------------------------------------------------
template<int BN, int EPI>
__global__ __launch_bounds__((BN == 256) ? 512 : 256, (BN == 256) ? 4 : 2)
void gemm_mfma(const __hip_bfloat16* __restrict__ A,
               const __hip_bfloat16* __restrict__ B,
               const float* __restrict__ bias,
               void* __restrict__ Cv,
               int K, int lda, int N,
               __hip_bfloat16* __restrict__ D2)
{
    constexpr int TH  = (BN == 256) ? 512 : 256;   // threads
    constexpr int NWN = (BN == 256) ? 4 : 2;       // n-waves
    constexpr int NI  = BN / (16 * NWN);           // n-frags per wave (4 or 2)
    __shared__ __bf16 As[128 * 64];
    __shared__ __bf16 Bs[BN * 64];

    const int tid  = threadIdx.x;
    const int lane = tid & 63;
    const int wave = tid >> 6;
    const size_t m0 = (size_t)blockIdx.x * 128;   // XCD = blockIdx.x % 8
    const int    n0 = blockIdx.y * BN;
    const int wm = (wave / NWN) * 64;
    const int wn = (wave % NWN) * (NI * 16);

    f32x4 acc[4][NI];
#pragma unroll
    for (int i = 0; i < 4; ++i)
#pragma unroll
        for (int j = 0; j < NI; ++j)
            acc[i][j] = f32x4{0.f, 0.f, 0.f, 0.f};

    const int frow = lane & 15;
    const int fq   = lane >> 4;

    for (int k0 = 0; k0 < K; k0 += 64) {
        __syncthreads();   // previous iteration's LDS reads complete
        // A tile: 128 rows x 8 chunks = 1024 chunks
#pragma unroll
        for (int q = 0; q < 1024 / TH; ++q) {
            const int lin = q * TH + tid;
            const int rr  = lin >> 3;
            const int gc  = (lin & 7) ^ (rr & 7);
            cp16_g2l(A + (m0 + rr) * (size_t)lda + k0 + gc * 8, &As[lin * 8]);
        }
        // B tile: BN rows x 8 chunks
#pragma unroll
        for (int q = 0; q < BN * 8 / TH; ++q) {
            const int lin = q * TH + tid;
            const int rr  = lin >> 3;
            const int gc  = (lin & 7) ^ (rr & 7);
            cp16_g2l(B + (size_t)(n0 + rr) * K + k0 + gc * 8, &Bs[lin * 8]);
        }
        __syncthreads();   // includes vmcnt(0) drain

#pragma unroll
        for (int ks = 0; ks < 2; ++ks) {
            bf16x8 af[4], bfr[NI];
#pragma unroll
            for (int mi = 0; mi < 4; ++mi) {
                const int R = wm + mi * 16 + frow;
                af[mi] = *(const bf16x8*)&As[R * 64 + (((ks * 4 + fq) ^ (R & 7)) * 8)];
            }
#pragma unroll
            for (int ni = 0; ni < NI; ++ni) {
                const int R = wn + ni * 16 + frow;
                bfr[ni] = *(const bf16x8*)&Bs[R * 64 + (((ks * 4 + fq) ^ (R & 7)) * 8)];
            }
#pragma unroll
            for (int mi = 0; mi < 4; ++mi)
#pragma unroll
                for (int ni = 0; ni < NI; ++ni)
                    acc[mi][ni] = __builtin_amdgcn_mfma_f32_16x16x32_bf16(
                        af[mi], bfr[ni], acc[mi][ni], 0, 0, 0);
        }
    }

    // C/D layout: col = lane&15, row = (lane>>4)*4 + reg
    const int er = fq * 4;
    const int ec = frow;
#pragma unroll
    for (int ni = 0; ni < NI; ++ni) {
        const int n = n0 + wn + ni * 16 + ec;
        const float bv = bias ? bias[n] : 0.f;
#pragma unroll
        for (int mi = 0; mi < 4; ++mi) {
#pragma unroll
            for (int r2 = 0; r2 < 4; ++r2) {
                const size_t m = m0 + wm + mi * 16 + er + r2;
                const float v = acc[mi][ni][r2] + bv;
                if (EPI == 0) {
                    ((float*)Cv)[m * (size_t)N + n] = v;
                } else if (EPI == 1) {
                    ((__hip_bfloat16*)Cv)[m * (size_t)N + n] = __float2bfloat16(v);
                } else {
                    if (n < 1024)
                        ((__hip_bfloat16*)Cv)[m * 1024 + n] = __float2bfloat16(gelu_tanh(v));
                    else
                        D2[(m + 3) * 1024 + (n - 1024)] = __float2bfloat16(v);
                }
            }
        }
    }
}

// ---------------------------------------------------------------------------
// Conv GEMM with shift reuse: bc[t,o] = sum_s sum_i W[o][s*1024+i]*bbp[t+s][i].
// Per 32-col k-tile: stage A halo (132 rows x 32 cols) ONCE + 4 B shift tiles
// (128 x 32 each), then 4 shifts x 16 MFMA per wave per barrier.  32 k-iters.
// 32-wide rows = 4 chunks; slot s at row r holds chunk s ^ ((r>>1)&3).
// (r6 body, 256 thr. Closed at ~68 us: pipeline variants r7/r11 regressed;
// r19's 2x occupancy left dur/MfmaUtil unchanged — the per-iter drain is
// structural, hit by all resident waves together.)
// ---------------------------------------------------------------------------
__global__ __launch_bounds__(256)
void conv_mfma(const __hip_bfloat16* __restrict__ bbp,
               const __hip_bfloat16* __restrict__ W,
               __hip_bfloat16* __restrict__ C)
{
    __shared__ __bf16 As[132 * 32];        // 8.25 KB halo tile
    __shared__ __bf16 Bs[4 * 128 * 32];    // 32 KB, 4 shift tiles

    const int tid  = threadIdx.x;
    const int lane = tid & 63;
    const int wave = tid >> 6;
    const size_t m0 = (size_t)blockIdx.x * 128;   // XCD = blockIdx.x % 8
    const int    n0 = blockIdx.y * 128;
    const int wm = (wave >> 1) * 64;
    const int wn = (wave & 1) * 64;

    f32x4 acc[4][4];
#pragma unroll
    for (int i = 0; i < 4; ++i)
#pragma unroll
        for (int j = 0; j < 4; ++j)
            acc[i][j] = f32x4{0.f, 0.f, 0.f, 0.f};

    const int frow = lane & 15;
    const int fq   = lane >> 4;

    for (int kc = 0; kc < 1024; kc += 32) {
        __syncthreads();
        // A halo: 132 rows x 4 chunks = 528 chunks (512 + 16 masked)
#pragma unroll
        for (int q = 0; q < 2; ++q) {
            const int lin = q * 256 + tid;
            const int rr  = lin >> 2;
            const int gc  = (lin & 3) ^ ((rr >> 1) & 3);
            cp16_g2l(bbp + (m0 + rr) * 1024 + kc + gc * 8, &As[lin * 8]);
        }
        if (tid < 16) {
            const int lin = 512 + tid;
            const int rr  = lin >> 2;
            const int gc  = (lin & 3) ^ ((rr >> 1) & 3);
            cp16_g2l(bbp + (m0 + rr) * 1024 + kc + gc * 8, &As[lin * 8]);
        }
        // B: 4 shift tiles, each 128 rows x 4 chunks = 512 chunks
#pragma unroll
        for (int s = 0; s < 4; ++s)
#pragma unroll
            for (int q = 0; q < 2; ++q) {
                const int lin = q * 256 + tid;
                const int rr  = lin >> 2;
                const int gc  = (lin & 3) ^ ((rr >> 1) & 3);
                cp16_g2l(W + (size_t)(n0 + rr) * 4096 + s * 1024 + kc + gc * 8,
                         &Bs[s * 4096 + lin * 8]);
            }
        __syncthreads();

#pragma unroll
        for (int s = 0; s < 4; ++s) {
            bf16x8 af[4], bfr[4];
#pragma unroll
            for (int mi = 0; mi < 4; ++mi) {
                const int R = wm + mi * 16 + frow + s;       // shifted row
                af[mi] = *(const bf16x8*)&As[R * 32 + ((fq ^ ((R >> 1) & 3)) * 8)];
            }
#pragma unroll
            for (int ni = 0; ni < 4; ++ni) {
                const int R = wn + ni * 16 + frow;
                bfr[ni] = *(const bf16x8*)&Bs[s * 4096 + R * 32 + ((fq ^ ((R >> 1) & 3)) * 8)];
            }
#pragma unroll
            for (int mi = 0; mi < 4; ++mi)
#pragma unroll
                for (int ni = 0; ni < 4; ++ni)
                    acc[mi][ni] = __builtin_amdgcn_mfma_f32_16x16x32_bf16(
                        af[mi], bfr[ni], acc[mi][ni], 0, 0, 0);
        }
    }

    const int er = fq * 4;
    const int ec = frow;
#pragma unroll
    for (int ni = 0; ni < 4; ++ni) {
        const int n = n0 + wn + ni * 16 + ec;
#pragma unroll
        for (int mi = 0; mi < 4; ++mi)
#pragma unroll
            for (int r2 = 0; r2 < 4; ++r2) {
                const size_t m = m0 + wm + mi * 16 + er + r2;
                C[m * 1024 + n] = __float2bfloat16(acc[mi][ni][r2]);
            }
    }
}

// ---------------------------------------------------------------------------
// Vectorized prep: 4 elems/thread for f32->bf16 conversions (float4 load,
// ushort4 store); conv repack 1 thread per (o,i): float4 read of 4 taps,
// 4 coalesced k-plane stores; bbp pad rows zeroed.
// ---------------------------------------------------------------------------
#define G_X   1572864                 // 8192*768/4
#define G_W1  (G_X + 393216)          // + 2048*768/4
#define G_WRG (G_W1 + 524288)         // + 2048*1024/4
#define G_WO  (G_WRG + 196608)        // + 768*1024/4
#define G_CW  (G_WO + 1048576)        // + 1024*1024 (o,i) pairs
#define G_PAD (G_CW + 768)            // + 3072/4 pad groups
#define PREP_BLOCKS (G_PAD / 256)     // 14595

__device__ __forceinline__ unsigned short bfu(float f) {
    __hip_bfloat16 h = __float2bfloat16(f);
    union { __hip_bfloat16 h; unsigned short u; } cv; cv.h = h; return cv.u;
}
__device__ __forceinline__ void cvt4(const float* __restrict__ s,
                                     __hip_bfloat16* __restrict__ d) {
    const float4 v = *(const float4*)s;
    ushort4 o; o.x = bfu(v.x); o.y = bfu(v.y); o.z = bfu(v.z); o.w = bfu(v.w);
    *(ushort4*)d = o;
}

__global__ void prep_kernel(const float* __restrict__ x, const float* __restrict__ w1,
                            const float* __restrict__ w_rg, const float* __restrict__ w_out,
                            const float* __restrict__ conv_w,
                            __hip_bfloat16* __restrict__ xb, __hip_bfloat16* __restrict__ w1b,
                            __hip_bfloat16* __restrict__ w_rgb, __hip_bfloat16* __restrict__ w_outb,
                            __hip_bfloat16* __restrict__ wbigb, __hip_bfloat16* __restrict__ bbp)
{
    const int g = blockIdx.x * 256 + threadIdx.x;
    if (g < G_X) {
        const size_t i = 4 * (size_t)g;            cvt4(x + i, xb + i);
    } else if (g < G_W1) {
        const size_t i = 4 * (size_t)(g - G_X);    cvt4(w1 + i, w1b + i);
    } else if (g < G_WRG) {
        const size_t i = 4 * (size_t)(g - G_W1);   cvt4(w_rg + i, w_rgb + i);
    } else if (g < G_WO) {
        const size_t i = 4 * (size_t)(g - G_WRG);  cvt4(w_out + i, w_outb + i);
    } else if (g < G_CW) {
        const int n = g - G_WO;                    // n = o*1024 + i
        const int o = n >> 10, i = n & 1023;
        const float4 v = *(const float4*)(conv_w + (size_t)n * 4); // 4 taps, contiguous
        __hip_bfloat16* base = wbigb + (size_t)o * 4096 + i;
        base[0]    = __float2bfloat16(v.x);        // k=0 plane (coalesced per k)
        base[1024] = __float2bfloat16(v.y);
        base[2048] = __float2bfloat16(v.z);
        base[3072] = __float2bfloat16(v.w);
    } else if (g < G_PAD) {
        const int i = (g - G_CW) * 4;
        ushort4 z; z.x = 0; z.y = 0; z.z = 0; z.w = 0;
        *(ushort4*)(bbp + i) = z;                  // rows 0..2 zero
    }
}

// Gates recomputed inline from g_pre (T x 2048 bf16) + bc (bf16):
__global__ void scan_pass1(const __hip_bfloat16* __restrict__ gp,
                           const __hip_bfloat16* __restrict__ bc,
                           const float* __restrict__ Lambda,
                           float* __restrict__ ch, float* __restrict__ ca)
{
    const int c = blockIdx.y * 256 + threadIdx.x;
    const int j = blockIdx.x;
    const float cl = -8.f * log1pf(expf(Lambda[c]));
    float h = 0.f, ap = 1.f;
    const int t0 = j * CL;
    for (int tt = 0; tt < CL; ++tt) {
        const int t = t0 + tt;
        const long gi = (long)t * 2048 + c;
        const float ig = 1.f / (1.f + expf(-__bfloat162float(gp[gi])));
        const float rg = 1.f / (1.f + expf(-__bfloat162float(gp[gi + 1024])));
        const float a  = expf(cl * rg);
        const float gx = sqrtf(fmaxf(0.f, 1.f - a * a)) * ig *
                         __bfloat162float(bc[(long)t * 1024 + c]);
        h  = fmaf(a, h, gx);
        ap *= a;
    }
    ch[j * 1024 + c] = h;
    ca[j * 1024 + c] = ap;
}

__global__ void scan_combine(float* __restrict__ ch, const float* __restrict__ ca)
{
    const int c = blockIdx.x * 256 + threadIdx.x;
    float carry = 0.f;
    for (int j = 0; j < NC; ++j) {
        const float hj = ch[j * 1024 + c];
        const float aj = ca[j * 1024 + c];
        ch[j * 1024 + c] = carry;
        carry = fmaf(aj, carry, hj);
    }
}

// Rescan with carry; z = ab * y -> bf16 (zb aliases bc: same-element RMW per thread).
__global__ void scan_pass2(const __hip_bfloat16* __restrict__ gp, const __hip_bfloat16* bc,
                           const float* __restrict__ Lambda,
                           const float* __restrict__ carry_in,
                           const __hip_bfloat16* __restrict__ ab,
                           __hip_bfloat16* zb)
{
    const int c = blockIdx.y * 256 + threadIdx.x;
    const int j = blockIdx.x;
    const float cl = -8.f * log1pf(expf(Lambda[c]));
    float h = carry_in[j * 1024 + c];
    const int t0 = j * CL;
    for (int tt = 0; tt < CL; ++tt) {
        const int t = t0 + tt;
        const long gi = (long)t * 2048 + c;
        const long bi = (long)t * 1024 + c;
        const float ig = 1.f / (1.f + expf(-__bfloat162float(gp[gi])));
        const float rg = 1.f / (1.f + expf(-__bfloat162float(gp[gi + 1024])));
        const float a  = expf(cl * rg);
        const float gx = sqrtf(fmaxf(0.f, 1.f - a * a)) * ig * __bfloat162float(bc[bi]);
        h = fmaf(a, h, gx);
        zb[bi] = __float2bfloat16(__bfloat162float(ab[bi]) * h);
    }
}

extern "C" void kernel_launch(void* const* d_in, const int* in_sizes, int n_in,
                              void* d_out, int out_size, void* d_ws, size_t ws_size,
                              hipStream_t stream)
{
    const float* x      = (const float*)d_in[0];
    const float* w1     = (const float*)d_in[1];
    const float* b1     = (const float*)d_in[2];
    const float* conv_w = (const float*)d_in[3];
    const float* w_rg   = (const float*)d_in[4];
    const float* b_rg   = (const float*)d_in[5];
    const float* w_out  = (const float*)d_in[6];
    const float* b_out  = (const float*)d_in[7];
    const float* Lambda = (const float*)d_in[8];
    float* out = (float*)d_out;
    (void)in_sizes; (void)n_in; (void)out_size; (void)ws_size;

    // ---- workspace layout (~113 MB) ----
    char* p = (char*)d_ws;
    auto alloc = [&](size_t bytes) { char* r = p; p += (bytes + 255) & ~255ULL; return r; };
    __hip_bfloat16* gpre  = (__hip_bfloat16*)alloc(8192ULL * 2048 * 2); // 32 MB
    __hip_bfloat16* ab    = (__hip_bfloat16*)alloc(8192ULL * 1024 * 2); // 16 MB
    __hip_bfloat16* bbp   = (__hip_bfloat16*)alloc(8224ULL * 1024 * 2); // 16.8 MB
    __hip_bfloat16* bcb   = (__hip_bfloat16*)alloc(8192ULL * 1024 * 2); // 16 MB (later zb)
    __hip_bfloat16* wbigb = (__hip_bfloat16*)alloc(1024ULL * 4096 * 2); // 8 MB
    __hip_bfloat16* xb    = (__hip_bfloat16*)alloc(8192ULL * 768 * 2);  // 12 MB
    __hip_bfloat16* w1b   = (__hip_bfloat16*)alloc(2048ULL * 768 * 2);  // 3 MB
    __hip_bfloat16* w_rgb = (__hip_bfloat16*)alloc(2048ULL * 1024 * 2); // 4 MB
    __hip_bfloat16* w_outb= (__hip_bfloat16*)alloc(768ULL * 1024 * 2);  // 1.5 MB
    float*          chv   = (float*)alloc(NC * 1024ULL * 4);
    float*          cav   = (float*)alloc(NC * 1024ULL * 4);
    __hip_bfloat16* zb    = bcb;   // overlay

    prep_kernel<<<PREP_BLOCKS, 256, 0, stream>>>(x, w1, w_rg, w_out, conv_w,
                                                 xb, w1b, w_rgb, w_outb, wbigb, bbp);

    // h = x @ w1.T + b1, fused split: ab = bf16(gelu), bbp = bf16 (rows +3)
    {
        dim3 grid(T_LEN / 128, 2048 / 256);
        gemm_mfma<256, 2><<<grid, 512, 0, stream>>>(xb, w1b, b1, ab, DM, DM, 2048, bbp);
    }

    // bc = causal conv (shift-reuse kernel) -> bf16
    {
        dim3 grid(T_LEN / 128, 1024 / 128);
        conv_mfma<<<grid, 256, 0, stream>>>(bbp, wbigb, bcb);
    }

    // g_pre = bc @ w_rg.T + b_rg -> bf16
    {
        dim3 grid(T_LEN / 128, 2048 / 256);
        gemm_mfma<256, 1><<<grid, 512, 0, stream>>>(bcb, w_rgb, b_rg, gpre, DR, DR, 2048, nullptr);
    }

    // chunked scan with fused gates; z = ab*y -> bf16 (overlays bcb)
    {
        dim3 gs(NC, DR / 256);
        scan_pass1<<<gs, 256, 0, stream>>>(gpre, bcb, Lambda, chv, cav);
        scan_combine<<<DR / 256, 256, 0, stream>>>(chv, cav);
        scan_pass2<<<gs, 256, 0, stream>>>(gpre, bcb, Lambda, chv, ab, zb);
    }

    // out = z @ w_out.T + b_out -> fp32
    {
        dim3 grid(T_LEN / 128, DM / 64);
        gemm_mfma<64, 0><<<grid, 256, 0, stream>>>(zb, w_outb, b_out, out, DR, DR, DM, nullptr);
    }
}

// Round 15
// 337.295 us; speedup vs baseline: 1.0477x; 1.0445x over previous
//
#include <hip/hip_runtime.h>
#include <hip/hip_bf16.h>
#include <stdint.h>

// ---------------------------------------------------------------------------
// RG-LRU block: T=8192, D_MODEL=768, D_RNN=1024, KW=4.
// Round 21 (final structural probe): out-GEMM -> 512 threads (r12 mechanism).
//  - BN=64 tile unchanged; 8 waves as 4m x 2n, 32x32/wave, acc[2][2].
//    3 blocks/CU x 8 waves = 24 waves/CU (6/SIMD) — highest-TLP kernel in
//    the pipeline, applied to the GEMM with the worst barrier:MFMA ratio.
//  - gemm template generalized (MI constexpr); staging/epilogue math
//    bit-identical.
// Identical-code noise ledger (r13/r16/r18/r20): 345.7/338.7/343.7/352.3 —
// sigma ~6 us, mean ~345. Everything else byte-identical to r16.
// ---------------------------------------------------------------------------

#define T_LEN 8192
#define DM 768
#define DR 1024
#define NC 128   // scan chunks
#define CL 64    // chunk length

typedef __bf16 bf16x8 __attribute__((ext_vector_type(8)));
typedef float  f32x4  __attribute__((ext_vector_type(4)));

#define AS1 __attribute__((address_space(1)))
#define AS3 __attribute__((address_space(3)))

__device__ __forceinline__ void cp16_g2l(const void* g, void* l) {
    __builtin_amdgcn_global_load_lds((const AS1 void*)g, (AS3 void*)l, 16, 0, 0);
}

__device__ __forceinline__ float gelu_tanh(float x) {
    const float inner = 0.7978845608028654f * (x + 0.044715f * x * x * x);
    return 0.5f * x * (1.f + tanhf(inner));
}

// ---------------------------------------------------------------------------
// Dense GEMM: C[m,n] = sum_k A[m,k]*B[n,k] (+bias[n]).  BM=128, BK=64.
// Grid: (M/128, N/BN) — m fastest (id%8 = m%8: all n-blocks of an m-tile
// share one XCD -> A-slice L2-resident).
// LDS rows are 64 elements = 8 16B chunks; chunk slot s at row r holds global
// chunk s ^ (r & 7)  -> every wave64 ds_read_b128 is perfectly bank-balanced.
// BN=256: 512 thr, 8 waves (2m x 4n), 64x64/wave, MI=4 NI=4, acc 64 VGPR ->
//         16 waves/CU (4/SIMD).
// BN=64:  512 thr, 8 waves (4m x 2n), 32x32/wave, MI=2 NI=2, acc 16 VGPR ->
//         24 waves/CU (6/SIMD) — r12 TLP mechanism on the out-GEMM.
// EPI: 0 = fp32 +bias; 1 = bf16 +bias; 2 = split (gelu->Cv / shift->D2).
// ---------------------------------------------------------------------------
template<int BN, int EPI>
__global__ __launch_bounds__(512, (BN == 256) ? 4 : 6)
void gemm_mfma(const __hip_bfloat16* __restrict__ A,
               const __hip_bfloat16* __restrict__ B,
               const float* __restrict__ bias,
               void* __restrict__ Cv,
               int K, int lda, int N,
               __hip_bfloat16* __restrict__ D2)
{
    constexpr int TH  = 512;                       // threads
    constexpr int NWN = (BN == 256) ? 4 : 2;       // n-waves
    constexpr int NWM = 8 / NWN;                   // m-waves (2 or 4)
    constexpr int NI  = BN / (16 * NWN);           // n-frags per wave (4 or 2)
    constexpr int MI  = 128 / (16 * NWM);          // m-frags per wave (4 or 2)
    __shared__ __bf16 As[128 * 64];
    __shared__ __bf16 Bs[BN * 64];

    const int tid  = threadIdx.x;
    const int lane = tid & 63;
    const int wave = tid >> 6;
    const size_t m0 = (size_t)blockIdx.x * 128;   // XCD = blockIdx.x % 8
    const int    n0 = blockIdx.y * BN;
    const int wm = (wave / NWN) * (MI * 16);
    const int wn = (wave % NWN) * (NI * 16);

    f32x4 acc[MI][NI];
#pragma unroll
    for (int i = 0; i < MI; ++i)
#pragma unroll
        for (int j = 0; j < NI; ++j)
            acc[i][j] = f32x4{0.f, 0.f, 0.f, 0.f};

    const int frow = lane & 15;
    const int fq   = lane >> 4;

    for (int k0 = 0; k0 < K; k0 += 64) {
        __syncthreads();   // previous iteration's LDS reads complete
        // A tile: 128 rows x 8 chunks = 1024 chunks
#pragma unroll
        for (int q = 0; q < 1024 / TH; ++q) {
            const int lin = q * TH + tid;
            const int rr  = lin >> 3;
            const int gc  = (lin & 7) ^ (rr & 7);
            cp16_g2l(A + (m0 + rr) * (size_t)lda + k0 + gc * 8, &As[lin * 8]);
        }
        // B tile: BN rows x 8 chunks
#pragma unroll
        for (int q = 0; q < BN * 8 / TH; ++q) {
            const int lin = q * TH + tid;
            const int rr  = lin >> 3;
            const int gc  = (lin & 7) ^ (rr & 7);
            cp16_g2l(B + (size_t)(n0 + rr) * K + k0 + gc * 8, &Bs[lin * 8]);
        }
        __syncthreads();   // includes vmcnt(0) drain

#pragma unroll
        for (int ks = 0; ks < 2; ++ks) {
            bf16x8 af[MI], bfr[NI];
#pragma unroll
            for (int mi = 0; mi < MI; ++mi) {
                const int R = wm + mi * 16 + frow;
                af[mi] = *(const bf16x8*)&As[R * 64 + (((ks * 4 + fq) ^ (R & 7)) * 8)];
            }
#pragma unroll
            for (int ni = 0; ni < NI; ++ni) {
                const int R = wn + ni * 16 + frow;
                bfr[ni] = *(const bf16x8*)&Bs[R * 64 + (((ks * 4 + fq) ^ (R & 7)) * 8)];
            }
#pragma unroll
            for (int mi = 0; mi < MI; ++mi)
#pragma unroll
                for (int ni = 0; ni < NI; ++ni)
                    acc[mi][ni] = __builtin_amdgcn_mfma_f32_16x16x32_bf16(
                        af[mi], bfr[ni], acc[mi][ni], 0, 0, 0);
        }
    }

    // C/D layout: col = lane&15, row = (lane>>4)*4 + reg
    const int er = fq * 4;
    const int ec = frow;
#pragma unroll
    for (int ni = 0; ni < NI; ++ni) {
        const int n = n0 + wn + ni * 16 + ec;
        const float bv = bias ? bias[n] : 0.f;
#pragma unroll
        for (int mi = 0; mi < MI; ++mi) {
#pragma unroll
            for (int r2 = 0; r2 < 4; ++r2) {
                const size_t m = m0 + wm + mi * 16 + er + r2;
                const float v = acc[mi][ni][r2] + bv;
                if (EPI == 0) {
                    ((float*)Cv)[m * (size_t)N + n] = v;
                } else if (EPI == 1) {
                    ((__hip_bfloat16*)Cv)[m * (size_t)N + n] = __float2bfloat16(v);
                } else {
                    if (n < 1024)
                        ((__hip_bfloat16*)Cv)[m * 1024 + n] = __float2bfloat16(gelu_tanh(v));
                    else
                        D2[(m + 3) * 1024 + (n - 1024)] = __float2bfloat16(v);
                }
            }
        }
    }
}

// ---------------------------------------------------------------------------
// Conv GEMM with shift reuse: bc[t,o] = sum_s sum_i W[o][s*1024+i]*bbp[t+s][i].
// Per 32-col k-tile: stage A halo (132 rows x 32 cols) ONCE + 4 B shift tiles
// (128 x 32 each), then 4 shifts x 16 MFMA per wave per barrier.  32 k-iters.
// 32-wide rows = 4 chunks; slot s at row r holds chunk s ^ ((r>>1)&3).
// (r6 body, 256 thr. Closed at ~68 us: pipeline variants r7/r11 regressed;
// r19's 2x occupancy left dur/MfmaUtil unchanged — the per-iter drain is
// structural, hit by all resident waves together.)
// ---------------------------------------------------------------------------
__global__ __launch_bounds__(256)
void conv_mfma(const __hip_bfloat16* __restrict__ bbp,
               const __hip_bfloat16* __restrict__ W,
               __hip_bfloat16* __restrict__ C)
{
    __shared__ __bf16 As[132 * 32];        // 8.25 KB halo tile
    __shared__ __bf16 Bs[4 * 128 * 32];    // 32 KB, 4 shift tiles

    const int tid  = threadIdx.x;
    const int lane = tid & 63;
    const int wave = tid >> 6;
    const size_t m0 = (size_t)blockIdx.x * 128;   // XCD = blockIdx.x % 8
    const int    n0 = blockIdx.y * 128;
    const int wm = (wave >> 1) * 64;
    const int wn = (wave & 1) * 64;

    f32x4 acc[4][4];
#pragma unroll
    for (int i = 0; i < 4; ++i)
#pragma unroll
        for (int j = 0; j < 4; ++j)
            acc[i][j] = f32x4{0.f, 0.f, 0.f, 0.f};

    const int frow = lane & 15;
    const int fq   = lane >> 4;

    for (int kc = 0; kc < 1024; kc += 32) {
        __syncthreads();
        // A halo: 132 rows x 4 chunks = 528 chunks (512 + 16 masked)
#pragma unroll
        for (int q = 0; q < 2; ++q) {
            const int lin = q * 256 + tid;
            const int rr  = lin >> 2;
            const int gc  = (lin & 3) ^ ((rr >> 1) & 3);
            cp16_g2l(bbp + (m0 + rr) * 1024 + kc + gc * 8, &As[lin * 8]);
        }
        if (tid < 16) {
            const int lin = 512 + tid;
            const int rr  = lin >> 2;
            const int gc  = (lin & 3) ^ ((rr >> 1) & 3);
            cp16_g2l(bbp + (m0 + rr) * 1024 + kc + gc * 8, &As[lin * 8]);
        }
        // B: 4 shift tiles, each 128 rows x 4 chunks = 512 chunks
#pragma unroll
        for (int s = 0; s < 4; ++s)
#pragma unroll
            for (int q = 0; q < 2; ++q) {
                const int lin = q * 256 + tid;
                const int rr  = lin >> 2;
                const int gc  = (lin & 3) ^ ((rr >> 1) & 3);
                cp16_g2l(W + (size_t)(n0 + rr) * 4096 + s * 1024 + kc + gc * 8,
                         &Bs[s * 4096 + lin * 8]);
            }
        __syncthreads();

#pragma unroll
        for (int s = 0; s < 4; ++s) {
            bf16x8 af[4], bfr[4];
#pragma unroll
            for (int mi = 0; mi < 4; ++mi) {
                const int R = wm + mi * 16 + frow + s;       // shifted row
                af[mi] = *(const bf16x8*)&As[R * 32 + ((fq ^ ((R >> 1) & 3)) * 8)];
            }
#pragma unroll
            for (int ni = 0; ni < 4; ++ni) {
                const int R = wn + ni * 16 + frow;
                bfr[ni] = *(const bf16x8*)&Bs[s * 4096 + R * 32 + ((fq ^ ((R >> 1) & 3)) * 8)];
            }
#pragma unroll
            for (int mi = 0; mi < 4; ++mi)
#pragma unroll
                for (int ni = 0; ni < 4; ++ni)
                    acc[mi][ni] = __builtin_amdgcn_mfma_f32_16x16x32_bf16(
                        af[mi], bfr[ni], acc[mi][ni], 0, 0, 0);
        }
    }

    const int er = fq * 4;
    const int ec = frow;
#pragma unroll
    for (int ni = 0; ni < 4; ++ni) {
        const int n = n0 + wn + ni * 16 + ec;
#pragma unroll
        for (int mi = 0; mi < 4; ++mi)
#pragma unroll
            for (int r2 = 0; r2 < 4; ++r2) {
                const size_t m = m0 + wm + mi * 16 + er + r2;
                C[m * 1024 + n] = __float2bfloat16(acc[mi][ni][r2]);
            }
    }
}

// ---------------------------------------------------------------------------
// Vectorized prep: 4 elems/thread for f32->bf16 conversions (float4 load,
// ushort4 store); conv repack 1 thread per (o,i): float4 read of 4 taps,
// 4 coalesced k-plane stores; bbp pad rows zeroed.
// ---------------------------------------------------------------------------
#define G_X   1572864                 // 8192*768/4
#define G_W1  (G_X + 393216)          // + 2048*768/4
#define G_WRG (G_W1 + 524288)         // + 2048*1024/4
#define G_WO  (G_WRG + 196608)        // + 768*1024/4
#define G_CW  (G_WO + 1048576)        // + 1024*1024 (o,i) pairs
#define G_PAD (G_CW + 768)            // + 3072/4 pad groups
#define PREP_BLOCKS (G_PAD / 256)     // 14595

__device__ __forceinline__ unsigned short bfu(float f) {
    __hip_bfloat16 h = __float2bfloat16(f);
    union { __hip_bfloat16 h; unsigned short u; } cv; cv.h = h; return cv.u;
}
__device__ __forceinline__ void cvt4(const float* __restrict__ s,
                                     __hip_bfloat16* __restrict__ d) {
    const float4 v = *(const float4*)s;
    ushort4 o; o.x = bfu(v.x); o.y = bfu(v.y); o.z = bfu(v.z); o.w = bfu(v.w);
    *(ushort4*)d = o;
}

__global__ void prep_kernel(const float* __restrict__ x, const float* __restrict__ w1,
                            const float* __restrict__ w_rg, const float* __restrict__ w_out,
                            const float* __restrict__ conv_w,
                            __hip_bfloat16* __restrict__ xb, __hip_bfloat16* __restrict__ w1b,
                            __hip_bfloat16* __restrict__ w_rgb, __hip_bfloat16* __restrict__ w_outb,
                            __hip_bfloat16* __restrict__ wbigb, __hip_bfloat16* __restrict__ bbp)
{
    const int g = blockIdx.x * 256 + threadIdx.x;
    if (g < G_X) {
        const size_t i = 4 * (size_t)g;            cvt4(x + i, xb + i);
    } else if (g < G_W1) {
        const size_t i = 4 * (size_t)(g - G_X);    cvt4(w1 + i, w1b + i);
    } else if (g < G_WRG) {
        const size_t i = 4 * (size_t)(g - G_W1);   cvt4(w_rg + i, w_rgb + i);
    } else if (g < G_WO) {
        const size_t i = 4 * (size_t)(g - G_WRG);  cvt4(w_out + i, w_outb + i);
    } else if (g < G_CW) {
        const int n = g - G_WO;                    // n = o*1024 + i
        const int o = n >> 10, i = n & 1023;
        const float4 v = *(const float4*)(conv_w + (size_t)n * 4); // 4 taps, contiguous
        __hip_bfloat16* base = wbigb + (size_t)o * 4096 + i;
        base[0]    = __float2bfloat16(v.x);        // k=0 plane (coalesced per k)
        base[1024] = __float2bfloat16(v.y);
        base[2048] = __float2bfloat16(v.z);
        base[3072] = __float2bfloat16(v.w);
    } else if (g < G_PAD) {
        const int i = (g - G_CW) * 4;
        ushort4 z; z.x = 0; z.y = 0; z.z = 0; z.w = 0;
        *(ushort4*)(bbp + i) = z;                  // rows 0..2 zero
    }
}

// Gates recomputed inline from g_pre (T x 2048 bf16) + bc (bf16):
__global__ void scan_pass1(const __hip_bfloat16* __restrict__ gp,
                           const __hip_bfloat16* __restrict__ bc,
                           const float* __restrict__ Lambda,
                           float* __restrict__ ch, float* __restrict__ ca)
{
    const int c = blockIdx.y * 256 + threadIdx.x;
    const int j = blockIdx.x;
    const float cl = -8.f * log1pf(expf(Lambda[c]));
    float h = 0.f, ap = 1.f;
    const int t0 = j * CL;
    for (int tt = 0; tt < CL; ++tt) {
        const int t = t0 + tt;
        const long gi = (long)t * 2048 + c;
        const float ig = 1.f / (1.f + expf(-__bfloat162float(gp[gi])));
        const float rg = 1.f / (1.f + expf(-__bfloat162float(gp[gi + 1024])));
        const float a  = expf(cl * rg);
        const float gx = sqrtf(fmaxf(0.f, 1.f - a * a)) * ig *
                         __bfloat162float(bc[(long)t * 1024 + c]);
        h  = fmaf(a, h, gx);
        ap *= a;
    }
    ch[j * 1024 + c] = h;
    ca[j * 1024 + c] = ap;
}

__global__ void scan_combine(float* __restrict__ ch, const float* __restrict__ ca)
{
    const int c = blockIdx.x * 256 + threadIdx.x;
    float carry = 0.f;
    for (int j = 0; j < NC; ++j) {
        const float hj = ch[j * 1024 + c];
        const float aj = ca[j * 1024 + c];
        ch[j * 1024 + c] = carry;
        carry = fmaf(aj, carry, hj);
    }
}

// Rescan with carry; z = ab * y -> bf16 (zb aliases bc: same-element RMW per thread).
__global__ void scan_pass2(const __hip_bfloat16* __restrict__ gp, const __hip_bfloat16* bc,
                           const float* __restrict__ Lambda,
                           const float* __restrict__ carry_in,
                           const __hip_bfloat16* __restrict__ ab,
                           __hip_bfloat16* zb)
{
    const int c = blockIdx.y * 256 + threadIdx.x;
    const int j = blockIdx.x;
    const float cl = -8.f * log1pf(expf(Lambda[c]));
    float h = carry_in[j * 1024 + c];
    const int t0 = j * CL;
    for (int tt = 0; tt < CL; ++tt) {
        const int t = t0 + tt;
        const long gi = (long)t * 2048 + c;
        const long bi = (long)t * 1024 + c;
        const float ig = 1.f / (1.f + expf(-__bfloat162float(gp[gi])));
        const float rg = 1.f / (1.f + expf(-__bfloat162float(gp[gi + 1024])));
        const float a  = expf(cl * rg);
        const float gx = sqrtf(fmaxf(0.f, 1.f - a * a)) * ig * __bfloat162float(bc[bi]);
        h = fmaf(a, h, gx);
        zb[bi] = __float2bfloat16(__bfloat162float(ab[bi]) * h);
    }
}

extern "C" void kernel_launch(void* const* d_in, const int* in_sizes, int n_in,
                              void* d_out, int out_size, void* d_ws, size_t ws_size,
                              hipStream_t stream)
{
    const float* x      = (const float*)d_in[0];
    const float* w1     = (const float*)d_in[1];
    const float* b1     = (const float*)d_in[2];
    const float* conv_w = (const float*)d_in[3];
    const float* w_rg   = (const float*)d_in[4];
    const float* b_rg   = (const float*)d_in[5];
    const float* w_out  = (const float*)d_in[6];
    const float* b_out  = (const float*)d_in[7];
    const float* Lambda = (const float*)d_in[8];
    float* out = (float*)d_out;
    (void)in_sizes; (void)n_in; (void)out_size; (void)ws_size;

    // ---- workspace layout (~113 MB) ----
    char* p = (char*)d_ws;
    auto alloc = [&](size_t bytes) { char* r = p; p += (bytes + 255) & ~255ULL; return r; };
    __hip_bfloat16* gpre  = (__hip_bfloat16*)alloc(8192ULL * 2048 * 2); // 32 MB
    __hip_bfloat16* ab    = (__hip_bfloat16*)alloc(8192ULL * 1024 * 2); // 16 MB
    __hip_bfloat16* bbp   = (__hip_bfloat16*)alloc(8224ULL * 1024 * 2); // 16.8 MB
    __hip_bfloat16* bcb   = (__hip_bfloat16*)alloc(8192ULL * 1024 * 2); // 16 MB (later zb)
    __hip_bfloat16* wbigb = (__hip_bfloat16*)alloc(1024ULL * 4096 * 2); // 8 MB
    __hip_bfloat16* xb    = (__hip_bfloat16*)alloc(8192ULL * 768 * 2);  // 12 MB
    __hip_bfloat16* w1b   = (__hip_bfloat16*)alloc(2048ULL * 768 * 2);  // 3 MB
    __hip_bfloat16* w_rgb = (__hip_bfloat16*)alloc(2048ULL * 1024 * 2); // 4 MB
    __hip_bfloat16* w_outb= (__hip_bfloat16*)alloc(768ULL * 1024 * 2);  // 1.5 MB
    float*          chv   = (float*)alloc(NC * 1024ULL * 4);
    float*          cav   = (float*)alloc(NC * 1024ULL * 4);
    __hip_bfloat16* zb    = bcb;   // overlay

    prep_kernel<<<PREP_BLOCKS, 256, 0, stream>>>(x, w1, w_rg, w_out, conv_w,
                                                 xb, w1b, w_rgb, w_outb, wbigb, bbp);

    // h = x @ w1.T + b1, fused split: ab = bf16(gelu), bbp = bf16 (rows +3)
    {
        dim3 grid(T_LEN / 128, 2048 / 256);
        gemm_mfma<256, 2><<<grid, 512, 0, stream>>>(xb, w1b, b1, ab, DM, DM, 2048, bbp);
    }

    // bc = causal conv (shift-reuse kernel) -> bf16
    {
        dim3 grid(T_LEN / 128, 1024 / 128);
        conv_mfma<<<grid, 256, 0, stream>>>(bbp, wbigb, bcb);
    }

    // g_pre = bc @ w_rg.T + b_rg -> bf16
    {
        dim3 grid(T_LEN / 128, 2048 / 256);
        gemm_mfma<256, 1><<<grid, 512, 0, stream>>>(bcb, w_rgb, b_rg, gpre, DR, DR, 2048, nullptr);
    }

    // chunked scan with fused gates; z = ab*y -> bf16 (overlays bcb)
    {
        dim3 gs(NC, DR / 256);
        scan_pass1<<<gs, 256, 0, stream>>>(gpre, bcb, Lambda, chv, cav);
        scan_combine<<<DR / 256, 256, 0, stream>>>(chv, cav);
        scan_pass2<<<gs, 256, 0, stream>>>(gpre, bcb, Lambda, chv, ab, zb);
    }

    // out = z @ w_out.T + b_out -> fp32  (512-thr, 24 waves/CU)
    {
        dim3 grid(T_LEN / 128, DM / 64);
        gemm_mfma<64, 0><<<grid, 512, 0, stream>>>(zb, w_outb, b_out, out, DR, DR, DM, nullptr);
    }
}